// Round 4
// baseline (739.246 us; speedup 1.0000x reference)
//
#include <hip/hip_runtime.h>
#include <math.h>

#define B_    16
#define S_    512
#define D_    768
#define L_    5
#define MAXW  5
#define TOPK  8
#define CAND  16
#define NSPAN (S_*MAXW)    // 2560
#define M_    (B_*S_)      // 8192

typedef __attribute__((ext_vector_type(8))) short s16x8;
typedef __attribute__((ext_vector_type(4))) float f32x4;

__device__ __forceinline__ ushort f2bf(float x) {
    union { float f; unsigned u; } c; c.f = x;
    unsigned r = c.u + 0x7fffu + ((c.u >> 16) & 1u);
    return (ushort)(r >> 16);
}
__device__ __forceinline__ float bf2f(ushort h) {
    union { unsigned u; float f; } c; c.u = ((unsigned)h) << 16;
    return c.f;
}

// ---------------------------------------------------------------------------
__global__ void init_k(int* __restrict__ flag, int v) {
    if (threadIdx.x == 0) *flag = v;
}

// ---------------------------------------------------------------------------
// split fp32 -> bf16 hi + bf16 lo, elementwise (token_embs)
// ---------------------------------------------------------------------------
__global__ __launch_bounds__(256)
void cvt_T(const float* __restrict__ X, ushort* __restrict__ hi, ushort* __restrict__ lo) {
    const int i = (blockIdx.x * 256 + threadIdx.x) * 4;
    float4 v = *reinterpret_cast<const float4*>(X + i);
    ushort4 h, l;
    h.x = f2bf(v.x); l.x = f2bf(v.x - bf2f(h.x));
    h.y = f2bf(v.y); l.y = f2bf(v.y - bf2f(h.y));
    h.z = f2bf(v.z); l.z = f2bf(v.z - bf2f(h.z));
    h.w = f2bf(v.w); l.w = f2bf(v.w - bf2f(h.w));
    *reinterpret_cast<ushort4*>(hi + i) = h;
    *reinterpret_cast<ushort4*>(lo + i) = l;
}

// ---------------------------------------------------------------------------
// W1 (1536x768 fp32) -> Wt hi/lo bf16 [n=1536][k=768], Wt[n][k]=W1[base+k][n&767]
// ---------------------------------------------------------------------------
__global__ __launch_bounds__(256)
void cvt_W(const float* __restrict__ W1, ushort* __restrict__ Whi, ushort* __restrict__ Wlo) {
    __shared__ float tl[32][33];
    const int k0 = blockIdx.x * 32, n0 = blockIdx.y * 32;
    const int tx = threadIdx.x & 31, ty = threadIdx.x >> 5;
    const int base = (n0 >= 768) ? 768 : 0;
    const int d0 = n0 & 767;
    #pragma unroll
    for (int it = 0; it < 4; ++it) {
        int rr = ty + it * 8;
        tl[rr][tx] = W1[(size_t)(base + k0 + rr) * 768 + d0 + tx];
    }
    __syncthreads();
    #pragma unroll
    for (int it = 0; it < 4; ++it) {
        int rr = ty + it * 8;
        float v = tl[tx][rr];
        ushort h = f2bf(v);
        size_t o = (size_t)(n0 + rr) * 768 + k0 + tx;
        Whi[o] = h;
        Wlo[o] = f2bf(v - bf2f(h));
    }
}

// ---------------------------------------------------------------------------
// MFMA GEMM (unchanged from R3 as a controlled experiment)
// ---------------------------------------------------------------------------
__global__ __launch_bounds__(256)
void mm_k(const ushort* __restrict__ Thi, const ushort* __restrict__ Tlo,
          const ushort* __restrict__ Whi, const ushort* __restrict__ Wlo,
          float* __restrict__ Aout, float* __restrict__ Bout) {
    __shared__ __align__(16) ushort As[128 * 32];
    __shared__ __align__(16) ushort Bs[128 * 32];
    const int tid = threadIdx.x;
    const int bm = blockIdx.x, bn = blockIdx.y;
    const int row0 = bm * 128;
    const int n0g = bn * 128;

    const int srow = tid >> 2;
    const int scol = (tid & 3) * 8;
    const size_t a_g0 = (size_t)(row0 + srow) * 768 + scol;
    const size_t b_g0 = (size_t)(n0g + srow) * 768 + scol;
    const int l_off = srow * 32 + scol;

    const int lane = tid & 63, wv = tid >> 6;
    const int wr = wv >> 1, wc = wv & 1;
    const int lr = lane & 15, lg = lane >> 4;
    const int ko = lg * 8;

    f32x4 acc[4][4];
    #pragma unroll
    for (int i = 0; i < 4; ++i)
        #pragma unroll
        for (int j = 0; j < 4; ++j) acc[i][j] = f32x4{0.f, 0.f, 0.f, 0.f};

    #pragma unroll 1
    for (int ph = 0; ph < 3; ++ph) {
        const ushort* Asrc = (ph == 1) ? Tlo : Thi;
        const ushort* Bsrc = (ph == 2) ? Wlo : Whi;
        #pragma unroll 1
        for (int jj = 0; jj < 24; ++jj) {
            const int col = jj * 32;
            uint4 a0 = *reinterpret_cast<const uint4*>(Asrc + a_g0 + col);
            uint4 a1 = *reinterpret_cast<const uint4*>(Asrc + a_g0 + col + 64 * 768);
            uint4 b0 = *reinterpret_cast<const uint4*>(Bsrc + b_g0 + col);
            uint4 b1 = *reinterpret_cast<const uint4*>(Bsrc + b_g0 + col + 64 * 768);
            __syncthreads();
            *reinterpret_cast<uint4*>(&As[l_off])           = a0;
            *reinterpret_cast<uint4*>(&As[l_off + 64 * 32]) = a1;
            *reinterpret_cast<uint4*>(&Bs[l_off])           = b0;
            *reinterpret_cast<uint4*>(&Bs[l_off + 64 * 32]) = b1;
            __syncthreads();
            s16x8 af[4], bf[4];
            #pragma unroll
            for (int i = 0; i < 4; ++i)
                af[i] = *reinterpret_cast<const s16x8*>(&As[(wr * 64 + i * 16 + lr) * 32 + ko]);
            #pragma unroll
            for (int j = 0; j < 4; ++j)
                bf[j] = *reinterpret_cast<const s16x8*>(&Bs[(wc * 64 + j * 16 + lr) * 32 + ko]);
            #pragma unroll
            for (int i = 0; i < 4; ++i)
                #pragma unroll
                for (int j = 0; j < 4; ++j)
                    acc[i][j] = __builtin_amdgcn_mfma_f32_16x16x32_bf16(af[i], bf[j], acc[i][j], 0, 0, 0);
        }
    }

    float* Om = (bn < 6) ? Aout : Bout;
    const int c0 = ((bn < 6) ? bn : bn - 6) * 128 + wc * 64;
    #pragma unroll
    for (int i = 0; i < 4; ++i) {
        const int rbase = row0 + wr * 64 + i * 16 + lg * 4;
        #pragma unroll
        for (int j = 0; j < 4; ++j) {
            const int cg = c0 + j * 16 + lr;
            #pragma unroll
            for (int r = 0; r < 4; ++r)
                Om[(size_t)(rbase + r) * 768 + cg] = acc[i][j][r];
        }
    }
}

// ---------------------------------------------------------------------------
// sample-validate A/Bm against exact fp32 dots; set flag on mismatch
// ---------------------------------------------------------------------------
__global__ __launch_bounds__(64)
void valid_k(const float* __restrict__ T, const float* __restrict__ W1,
             const float* __restrict__ A, const float* __restrict__ Bm,
             int* __restrict__ flag) {
    const int blk = blockIdx.x, lane = threadIdx.x;
    #pragma unroll 1
    for (int j = 0; j < 8; ++j) {
        const int id = blk * 8 + j;
        const int m = (id * 509) & 8191;
        const int n = (id * 251) % 1536;
        const float* w = (n < 768) ? (W1 + n) : (W1 + 768 * 768 + (n - 768));
        float p = 0.f;
        for (int k = lane; k < 768; k += 64)
            p = fmaf(T[(size_t)m * 768 + k], w[(size_t)k * 768], p);
        #pragma unroll
        for (int off = 32; off; off >>= 1) p += __shfl_xor(p, off);
        if (lane == 0) {
            float ap = (n < 768) ? A[(size_t)m * 768 + n] : Bm[(size_t)m * 768 + (n - 768)];
            if (fabsf(p - ap) > 0.02f) atomicOr(flag, 1);
        }
    }
}

// ---------------------------------------------------------------------------
// guarded fp32 GEMM: runs fully only if flag != 0 (repair / fallback)
// ---------------------------------------------------------------------------
__global__ __launch_bounds__(256, 3)
void repair_k(const float* __restrict__ Tm, const float* __restrict__ W1,
              float* __restrict__ Aout, float* __restrict__ Bout,
              const int* __restrict__ flag) {
    if (*flag == 0) return;
    constexpr int K = D_, N = D_;
    __shared__ float As[16][128];
    __shared__ float Bs[16][128];
    const int bm  = blockIdx.x;
    const int bn2 = blockIdx.y;
    const float* W = W1 + (bn2 >= 6 ? (size_t)D_ * D_ : 0);
    float* Om      = (bn2 >= 6) ? Bout : Aout;
    const int bn   = (bn2 >= 6) ? bn2 - 6 : bn2;
    const int tid = threadIdx.x;
    const int row0 = bm * 128, col0 = bn * 128;
    const int tx = tid & 15, ty = tid >> 4;
    float acc[8][8];
    #pragma unroll
    for (int i = 0; i < 8; ++i)
        #pragma unroll
        for (int j = 0; j < 8; ++j) acc[i][j] = 0.f;
    const int arow = tid >> 1;
    const int acol = (tid & 1) * 4;
    const int brow = tid >> 5;
    const int bcol = (tid & 31) * 4;
    const float* Aptr = Tm + (size_t)(row0 + arow) * K + acol;
    const float* Bptr = W  + (size_t)brow * N + col0 + bcol;
    for (int k0 = 0; k0 < K; k0 += 16) {
        #pragma unroll
        for (int r = 0; r < 2; ++r) {
            float4 av = *reinterpret_cast<const float4*>(Aptr + k0 + r * 8);
            As[acol + r*8 + 0][arow] = av.x;
            As[acol + r*8 + 1][arow] = av.y;
            As[acol + r*8 + 2][arow] = av.z;
            As[acol + r*8 + 3][arow] = av.w;
        }
        #pragma unroll
        for (int r = 0; r < 2; ++r) {
            float4 bv = *reinterpret_cast<const float4*>(Bptr + (size_t)(k0 + r*8) * N);
            *reinterpret_cast<float4*>(&Bs[brow + r*8][bcol]) = bv;
        }
        __syncthreads();
        #pragma unroll
        for (int k = 0; k < 16; ++k) {
            float a[8], b[8];
            *reinterpret_cast<float4*>(&a[0]) = *reinterpret_cast<const float4*>(&As[k][ty*8]);
            *reinterpret_cast<float4*>(&a[4]) = *reinterpret_cast<const float4*>(&As[k][ty*8+4]);
            *reinterpret_cast<float4*>(&b[0]) = *reinterpret_cast<const float4*>(&Bs[k][tx*4]);
            *reinterpret_cast<float4*>(&b[4]) = *reinterpret_cast<const float4*>(&Bs[k][tx*4+64]);
            #pragma unroll
            for (int i = 0; i < 8; ++i)
                #pragma unroll
                for (int j = 0; j < 8; ++j)
                    acc[i][j] = fmaf(a[i], b[j], acc[i][j]);
        }
        __syncthreads();
    }
    #pragma unroll
    for (int i = 0; i < 8; ++i) {
        size_t ro = (size_t)(row0 + ty*8 + i) * N + col0;
        float4 v0 = make_float4(acc[i][0], acc[i][1], acc[i][2], acc[i][3]);
        float4 v1 = make_float4(acc[i][4], acc[i][5], acc[i][6], acc[i][7]);
        *reinterpret_cast<float4*>(&Om[ro + tx*4])      = v0;
        *reinterpret_cast<float4*>(&Om[ro + tx*4 + 64]) = v1;
    }
}

// ---------------------------------------------------------------------------
__global__ void w2ws_k(const float* __restrict__ W2, const float* __restrict__ Ws,
                       const float* __restrict__ b2, const float* __restrict__ bs,
                       float* __restrict__ w2ws, float* __restrict__ cc) {
    const int d = blockIdx.x;
    const int lane = threadIdx.x;
    float p = 0.f;
    if (d < D_) {
        const float* row = W2 + (size_t)d * D_;
        for (int i = lane; i < D_; i += 64) p += row[i] * Ws[i];
    } else {
        for (int i = lane; i < D_; i += 64) p += b2[i] * Ws[i];
    }
    #pragma unroll
    for (int off = 32; off; off >>= 1) p += __shfl_xor(p, off);
    if (lane == 0) {
        if (d < D_) w2ws[d] = p;
        else        *cc = p + *bs;
    }
}

__global__ void seqlen_k(const int* __restrict__ mask, int* __restrict__ seqlen) {
    const int b = blockIdx.x;
    const int lane = threadIdx.x;
    int p = 0;
    for (int i = lane; i < S_; i += 64) p += mask[b * S_ + i];
    #pragma unroll
    for (int off = 32; off; off >>= 1) p += __shfl_xor(p, off);
    if (lane == 0) seqlen[b] = p;
}

// ---------------------------------------------------------------------------
// approx span scores from A/Bm (drives candidate selection only)
// ---------------------------------------------------------------------------
__global__ __launch_bounds__(64)
void score_k(const float* __restrict__ A, const float* __restrict__ Bm,
             const float* __restrict__ b1, const float* __restrict__ w2ws,
             const float* __restrict__ cc, const int* __restrict__ seqlen,
             float* __restrict__ scores) {
    const int bsid = blockIdx.x;
    const int b = bsid >> 9, s = bsid & 511;
    const int lane = threadIdx.x;
    float a[12], w[12], bb[12];
    const float* Arow = A + (size_t)bsid * D_;
    #pragma unroll
    for (int i = 0; i < 12; ++i) {
        int d = lane + i * 64;
        a[i]  = Arow[d];
        w[i]  = w2ws[d];
        bb[i] = b1[d];
    }
    const int sl = seqlen[b];
    const float c = *cc;
    #pragma unroll
    for (int w_ = 0; w_ < MAXW; ++w_) {
        const int e = min(s + w_, S_ - 1);
        const float* Brow = Bm + ((size_t)(b << 9) + e) * D_;
        float p = 0.f;
        #pragma unroll
        for (int i = 0; i < 12; ++i) {
            float h = a[i] + Brow[lane + i * 64] + bb[i];
            p = fmaf(fmaxf(h, 0.f), w[i], p);
        }
        #pragma unroll
        for (int off = 32; off; off >>= 1) p += __shfl_xor(p, off);
        if (lane == 0)
            scores[b * NSPAN + s * MAXW + w_] = (s + w_ < sl) ? (p + c) : -1e30f;
    }
}

// ---------------------------------------------------------------------------
// top-16 candidates per batch (approx scores; tie -> lowest index)
// ---------------------------------------------------------------------------
__global__ __launch_bounds__(256)
void topk_k(const float* __restrict__ scores, int* __restrict__ cand_idx) {
    __shared__ float sv[NSPAN];
    __shared__ float rv[4];
    __shared__ int   ri[4];
    const int b = blockIdx.x, tid = threadIdx.x;
    for (int i = tid; i < NSPAN; i += 256) sv[i] = scores[b * NSPAN + i];
    __syncthreads();
    for (int k = 0; k < CAND; ++k) {
        float best = -INFINITY; int bi = 1 << 30;
        for (int i = tid; i < NSPAN; i += 256) {
            float v = sv[i];
            if (v > best || (v == best && i < bi)) { best = v; bi = i; }
        }
        #pragma unroll
        for (int off = 32; off; off >>= 1) {
            float ov = __shfl_xor(best, off);
            int   oi = __shfl_xor(bi, off);
            if (ov > best || (ov == best && oi < bi)) { best = ov; bi = oi; }
        }
        if ((tid & 63) == 0) { rv[tid >> 6] = best; ri[tid >> 6] = bi; }
        __syncthreads();
        if (tid == 0) {
            #pragma unroll
            for (int wv = 1; wv < 4; ++wv)
                if (rv[wv] > best || (rv[wv] == best && ri[wv] < bi)) { best = rv[wv]; bi = ri[wv]; }
            cand_idx[b * CAND + k] = bi;
            sv[bi] = -INFINITY;
        }
        __syncthreads();
    }
}

// ---------------------------------------------------------------------------
// exact fp32 recompute of candidate spans: h vectors + exact scores.
// one block per (batch, group-of-4 candidates). Independent of A/Bm.
// ---------------------------------------------------------------------------
__global__ __launch_bounds__(256)
void rerank_k(const float* __restrict__ T, const float* __restrict__ W1,
              const float* __restrict__ b1, const float* __restrict__ w2ws,
              const float* __restrict__ cc, const int* __restrict__ cand_idx,
              float* __restrict__ cand_h, float* __restrict__ cand_score) {
    __shared__ float hsL[4][768];
    __shared__ float heL[4][768];
    __shared__ float red[4][4];
    const int blk = blockIdx.x;
    const int b = blk >> 2, g = blk & 3;
    const int tid = threadIdx.x;

    int sA[4], eA[4];
    #pragma unroll
    for (int j = 0; j < 4; ++j) {
        const int n = cand_idx[b * CAND + g * 4 + j];
        const int s = n / MAXW, w = n % MAXW;
        sA[j] = s; eA[j] = min(s + w, S_ - 1);
    }
    #pragma unroll
    for (int j = 0; j < 4; ++j) {
        const float* hsrc = T + ((size_t)(b * S_ + sA[j])) * D_;
        const float* esrc = T + ((size_t)(b * S_ + eA[j])) * D_;
        for (int d = tid; d < D_; d += 256) { hsL[j][d] = hsrc[d]; heL[j][d] = esrc[d]; }
    }
    __syncthreads();

    float acc[4][3];
    #pragma unroll
    for (int j = 0; j < 4; ++j)
        #pragma unroll
        for (int q = 0; q < 3; ++q) acc[j][q] = 0.f;

    #pragma unroll 1
    for (int k = 0; k < D_; ++k) {
        const float w00 = W1[(size_t)k * D_ + tid];
        const float w01 = W1[(size_t)k * D_ + tid + 256];
        const float w02 = W1[(size_t)k * D_ + tid + 512];
        const float w10 = W1[(size_t)(D_ + k) * D_ + tid];
        const float w11 = W1[(size_t)(D_ + k) * D_ + tid + 256];
        const float w12 = W1[(size_t)(D_ + k) * D_ + tid + 512];
        #pragma unroll
        for (int j = 0; j < 4; ++j) {
            const float hs = hsL[j][k], he = heL[j][k];
            acc[j][0] = fmaf(hs, w00, fmaf(he, w10, acc[j][0]));
            acc[j][1] = fmaf(hs, w01, fmaf(he, w11, acc[j][1]));
            acc[j][2] = fmaf(hs, w02, fmaf(he, w12, acc[j][2]));
        }
    }

    float part[4] = {0.f, 0.f, 0.f, 0.f};
    #pragma unroll
    for (int j = 0; j < 4; ++j) {
        #pragma unroll
        for (int q = 0; q < 3; ++q) {
            const int d = tid + q * 256;
            const float h = fmaxf(acc[j][q] + b1[d], 0.f);
            cand_h[((size_t)(b * CAND + g * 4 + j)) * D_ + d] = h;
            part[j] = fmaf(h, w2ws[d], part[j]);
        }
    }
    #pragma unroll
    for (int j = 0; j < 4; ++j) {
        #pragma unroll
        for (int off = 32; off; off >>= 1) part[j] += __shfl_xor(part[j], off);
        if ((tid & 63) == 0) red[j][tid >> 6] = part[j];
    }
    __syncthreads();
    if (tid == 0) {
        #pragma unroll
        for (int j = 0; j < 4; ++j)
            cand_score[b * CAND + g * 4 + j] =
                red[j][0] + red[j][1] + red[j][2] + red[j][3] + *cc;
    }
}

// ---------------------------------------------------------------------------
// exact top-8 from the 16 candidates (score desc, tie -> lower span index)
// ---------------------------------------------------------------------------
__global__ void sel_k(const float* __restrict__ cand_score, const int* __restrict__ cand_idx,
                      float* __restrict__ top_rel, int* __restrict__ sel_slot) {
    const int b = blockIdx.x;
    if (threadIdx.x != 0) return;
    float sc[CAND]; int nn[CAND]; bool used[CAND];
    #pragma unroll
    for (int c = 0; c < CAND; ++c) {
        sc[c] = cand_score[b * CAND + c];
        nn[c] = cand_idx[b * CAND + c];
        used[c] = false;
    }
    for (int k = 0; k < TOPK; ++k) {
        float best = -INFINITY; int bi = -1, bn = 1 << 30;
        #pragma unroll
        for (int c = 0; c < CAND; ++c) {
            if (!used[c] && (sc[c] > best || (sc[c] == best && nn[c] < bn))) {
                best = sc[c]; bi = c; bn = nn[c];
            }
        }
        used[bi] = true;
        top_rel[b * TOPK + k] = best;
        sel_slot[b * TOPK + k] = bi;
    }
}

// ---------------------------------------------------------------------------
// span_reprs for selected spans (from exact h) + sim vs labels
// ---------------------------------------------------------------------------
__global__ __launch_bounds__(256)
void repr2_k(const float* __restrict__ cand_h, const int* __restrict__ sel_slot,
             const float* __restrict__ W2, const float* __restrict__ b2,
             const float* __restrict__ labels, float* __restrict__ sim) {
    const int blk = blockIdx.x;
    const int b = blk >> 3, kk = blk & 7;
    const int tid = threadIdx.x;
    __shared__ float h[D_];
    __shared__ float sr[D_];
    __shared__ float red[4];

    const int c = sel_slot[b * TOPK + kk];
    const float* hp = cand_h + ((size_t)(b * CAND + c)) * D_;
    for (int d = tid; d < D_; d += 256) h[d] = hp[d];
    __syncthreads();

    float r0 = b2[tid], r1 = b2[tid + 256], r2 = b2[tid + 512];
    for (int d = 0; d < D_; ++d) {
        const float hv = h[d];
        const float* Wrow = W2 + (size_t)d * D_;
        r0 = fmaf(hv, Wrow[tid],       r0);
        r1 = fmaf(hv, Wrow[tid + 256], r1);
        r2 = fmaf(hv, Wrow[tid + 512], r2);
    }
    sr[tid] = r0; sr[tid + 256] = r1; sr[tid + 512] = r2;
    __syncthreads();

    const float* lab = labels + (size_t)b * L_ * D_;
    for (int l = 0; l < L_; ++l) {
        float p = 0.f;
        for (int d = tid; d < D_; d += 256) p = fmaf(lab[l * D_ + d], sr[d], p);
        #pragma unroll
        for (int off = 32; off; off >>= 1) p += __shfl_xor(p, off);
        if ((tid & 63) == 0) red[tid >> 6] = p;
        __syncthreads();
        if (tid == 0) sim[(b * L_ + l) * TOPK + kk] = red[0] + red[1] + red[2] + red[3];
        __syncthreads();
    }
}

// ---------------------------------------------------------------------------
__global__ void final_k(const float* __restrict__ top_rel, const float* __restrict__ sim,
                        float* __restrict__ out) {
    const int b = blockIdx.x, tid = threadIdx.x;
    float m = -INFINITY;
    #pragma unroll
    for (int k = 0; k < TOPK; ++k) m = fmaxf(m, top_rel[b * TOPK + k]);
    float wgt[TOPK]; float Z = 0.f;
    #pragma unroll
    for (int k = 0; k < TOPK; ++k) { wgt[k] = expf(top_rel[b * TOPK + k] - m); Z += wgt[k]; }
    if (tid < L_) {
        float acc = 0.f;
        #pragma unroll
        for (int k = 0; k < TOPK; ++k) acc += sim[(b * L_ + tid) * TOPK + k] * wgt[k];
        const float sc = acc / Z;
        out[b * L_ + tid]            = 1.f / (1.f + expf(-sc));
        out[B_ * L_ + b * L_ + tid]  = 1.0f;
    }
}

// ---------------------------------------------------------------------------
extern "C" void kernel_launch(void* const* d_in, const int* in_sizes, int n_in,
                              void* d_out, int out_size, void* d_ws, size_t ws_size,
                              hipStream_t stream) {
    (void)in_sizes; (void)n_in; (void)out_size;
    const float* token_embs = (const float*)d_in[0];
    const int*   token_mask = (const int*)  d_in[1];
    const float* label_embs = (const float*)d_in[2];
    const float* W1 = (const float*)d_in[3];
    const float* b1 = (const float*)d_in[4];
    const float* W2 = (const float*)d_in[5];
    const float* b2 = (const float*)d_in[6];
    const float* Ws = (const float*)d_in[7];
    const float* bs = (const float*)d_in[8];
    float* out = (float*)d_out;

    float* A          = (float*)d_ws;                   // 6291456 f32
    float* Bm         = A + (size_t)M_ * D_;            // 6291456 f32
    float* scores     = Bm + (size_t)M_ * D_;           // 40960
    float* w2ws       = scores + B_ * NSPAN;            // 768
    float* cc         = w2ws + D_;                      // 1
    int*   seqlen     = (int*)(cc + 1);                 // 16
    int*   flag       = seqlen + B_;                    // 1
    float* top_rel    = (float*)(flag + 1);             // 128
    int*   sel_slot   = (int*)(top_rel + B_ * TOPK);    // 128
    int*   cand_idx   = sel_slot + B_ * TOPK;           // 256
    float* cand_score = (float*)(cand_idx + B_ * CAND); // 256
    float* sim        = cand_score + B_ * CAND;         // 640
    float* cand_h     = A;  // A/Bm dead after score_k; reuse A region (196608 f)

    ushort* Thi  = (ushort*)(A + 12648448);
    ushort* Tlo  = Thi + (size_t)M_ * D_;
    ushort* WhiT = Tlo + (size_t)M_ * D_;
    ushort* WloT = WhiT + (size_t)2 * D_ * D_;
    const size_t need = 12648448ULL * 4 + (2ULL * M_ * D_ + 4ULL * D_ * D_) * 2;
    const bool use_mfma = (ws_size >= need);

    init_k<<<1, 64, 0, stream>>>(flag, use_mfma ? 0 : 1);
    if (use_mfma) {
        cvt_T<<<(M_ * D_) / (256 * 4), 256, 0, stream>>>(token_embs, Thi, Tlo);
        cvt_W<<<dim3(24, 48), 256, 0, stream>>>(W1, WhiT, WloT);
        mm_k <<<dim3(64, 12), 256, 0, stream>>>(Thi, Tlo, WhiT, WloT, A, Bm);
        valid_k<<<256, 64, 0, stream>>>(token_embs, W1, A, Bm, flag);
    }
    repair_k<<<dim3(64, 12), 256, 0, stream>>>(token_embs, W1, A, Bm, flag);
    w2ws_k  <<<D_ + 1, 64, 0, stream>>>(W2, Ws, b2, bs, w2ws, cc);
    seqlen_k<<<B_, 64, 0, stream>>>(token_mask, seqlen);
    score_k <<<M_, 64, 0, stream>>>(A, Bm, b1, w2ws, cc, seqlen, scores);
    topk_k  <<<B_, 256, 0, stream>>>(scores, cand_idx);
    rerank_k<<<B_ * 4, 256, 0, stream>>>(token_embs, W1, b1, w2ws, cc, cand_idx,
                                         cand_h, cand_score);
    sel_k   <<<B_, 64, 0, stream>>>(cand_score, cand_idx, top_rel, sel_slot);
    repr2_k <<<B_ * TOPK, 256, 0, stream>>>(cand_h, sel_slot, W2, b2, label_embs, sim);
    final_k <<<B_, 64, 0, stream>>>(top_rel, sim, out);
}

// Round 5
// 551.711 us; speedup vs baseline: 1.3399x; 1.3399x over previous
//
#include <hip/hip_runtime.h>
#include <math.h>

#define B_    16
#define S_    512
#define D_    768
#define L_    5
#define MAXW  5
#define TOPK  8
#define CAND  16
#define NSPAN (S_*MAXW)    // 2560
#define M_    (B_*S_)      // 8192

typedef __attribute__((ext_vector_type(8))) short s16x8;
typedef __attribute__((ext_vector_type(4))) float f32x4;

__device__ __forceinline__ ushort f2bf(float x) {
    union { float f; unsigned u; } c; c.f = x;
    unsigned r = c.u + 0x7fffu + ((c.u >> 16) & 1u);
    return (ushort)(r >> 16);
}
__device__ __forceinline__ float bf2f(ushort h) {
    union { unsigned u; float f; } c; c.u = ((unsigned)h) << 16;
    return c.f;
}

// ---------------------------------------------------------------------------
__global__ void init_k(int* __restrict__ flag, int v) {
    if (threadIdx.x == 0) *flag = v;
}

// ---------------------------------------------------------------------------
__global__ __launch_bounds__(256)
void cvt_T(const float* __restrict__ X, ushort* __restrict__ hi, ushort* __restrict__ lo) {
    const int i = (blockIdx.x * 256 + threadIdx.x) * 4;
    float4 v = *reinterpret_cast<const float4*>(X + i);
    ushort4 h, l;
    h.x = f2bf(v.x); l.x = f2bf(v.x - bf2f(h.x));
    h.y = f2bf(v.y); l.y = f2bf(v.y - bf2f(h.y));
    h.z = f2bf(v.z); l.z = f2bf(v.z - bf2f(h.z));
    h.w = f2bf(v.w); l.w = f2bf(v.w - bf2f(h.w));
    *reinterpret_cast<ushort4*>(hi + i) = h;
    *reinterpret_cast<ushort4*>(lo + i) = l;
}

// ---------------------------------------------------------------------------
__global__ __launch_bounds__(256)
void cvt_W(const float* __restrict__ W1, ushort* __restrict__ Whi, ushort* __restrict__ Wlo) {
    __shared__ float tl[32][33];
    const int k0 = blockIdx.x * 32, n0 = blockIdx.y * 32;
    const int tx = threadIdx.x & 31, ty = threadIdx.x >> 5;
    const int base = (n0 >= 768) ? 768 : 0;
    const int d0 = n0 & 767;
    #pragma unroll
    for (int it = 0; it < 4; ++it) {
        int rr = ty + it * 8;
        tl[rr][tx] = W1[(size_t)(base + k0 + rr) * 768 + d0 + tx];
    }
    __syncthreads();
    #pragma unroll
    for (int it = 0; it < 4; ++it) {
        int rr = ty + it * 8;
        float v = tl[tx][rr];
        ushort h = f2bf(v);
        size_t o = (size_t)(n0 + rr) * 768 + k0 + tx;
        Whi[o] = h;
        Wlo[o] = f2bf(v - bf2f(h));
    }
}

// ---------------------------------------------------------------------------
// MFMA GEMM (unchanged from R3/R4 — controlled experiment, validated below)
// ---------------------------------------------------------------------------
__global__ __launch_bounds__(256)
void mm_k(const ushort* __restrict__ Thi, const ushort* __restrict__ Tlo,
          const ushort* __restrict__ Whi, const ushort* __restrict__ Wlo,
          float* __restrict__ Aout, float* __restrict__ Bout) {
    __shared__ __align__(16) ushort As[128 * 32];
    __shared__ __align__(16) ushort Bs[128 * 32];
    const int tid = threadIdx.x;
    const int bm = blockIdx.x, bn = blockIdx.y;
    const int row0 = bm * 128;
    const int n0g = bn * 128;

    const int srow = tid >> 2;
    const int scol = (tid & 3) * 8;
    const size_t a_g0 = (size_t)(row0 + srow) * 768 + scol;
    const size_t b_g0 = (size_t)(n0g + srow) * 768 + scol;
    const int l_off = srow * 32 + scol;

    const int lane = tid & 63, wv = tid >> 6;
    const int wr = wv >> 1, wc = wv & 1;
    const int lr = lane & 15, lg = lane >> 4;
    const int ko = lg * 8;

    f32x4 acc[4][4];
    #pragma unroll
    for (int i = 0; i < 4; ++i)
        #pragma unroll
        for (int j = 0; j < 4; ++j) acc[i][j] = f32x4{0.f, 0.f, 0.f, 0.f};

    #pragma unroll 1
    for (int ph = 0; ph < 3; ++ph) {
        const ushort* Asrc = (ph == 1) ? Tlo : Thi;
        const ushort* Bsrc = (ph == 2) ? Wlo : Whi;
        #pragma unroll 1
        for (int jj = 0; jj < 24; ++jj) {
            const int col = jj * 32;
            uint4 a0 = *reinterpret_cast<const uint4*>(Asrc + a_g0 + col);
            uint4 a1 = *reinterpret_cast<const uint4*>(Asrc + a_g0 + col + 64 * 768);
            uint4 b0 = *reinterpret_cast<const uint4*>(Bsrc + b_g0 + col);
            uint4 b1 = *reinterpret_cast<const uint4*>(Bsrc + b_g0 + col + 64 * 768);
            __syncthreads();
            *reinterpret_cast<uint4*>(&As[l_off])           = a0;
            *reinterpret_cast<uint4*>(&As[l_off + 64 * 32]) = a1;
            *reinterpret_cast<uint4*>(&Bs[l_off])           = b0;
            *reinterpret_cast<uint4*>(&Bs[l_off + 64 * 32]) = b1;
            __syncthreads();
            s16x8 af[4], bf[4];
            #pragma unroll
            for (int i = 0; i < 4; ++i)
                af[i] = *reinterpret_cast<const s16x8*>(&As[(wr * 64 + i * 16 + lr) * 32 + ko]);
            #pragma unroll
            for (int j = 0; j < 4; ++j)
                bf[j] = *reinterpret_cast<const s16x8*>(&Bs[(wc * 64 + j * 16 + lr) * 32 + ko]);
            #pragma unroll
            for (int i = 0; i < 4; ++i)
                #pragma unroll
                for (int j = 0; j < 4; ++j)
                    acc[i][j] = __builtin_amdgcn_mfma_f32_16x16x32_bf16(af[i], bf[j], acc[i][j], 0, 0, 0);
        }
    }

    float* Om = (bn < 6) ? Aout : Bout;
    const int c0 = ((bn < 6) ? bn : bn - 6) * 128 + wc * 64;
    #pragma unroll
    for (int i = 0; i < 4; ++i) {
        const int rbase = row0 + wr * 64 + i * 16 + lg * 4;
        #pragma unroll
        for (int j = 0; j < 4; ++j) {
            const int cg = c0 + j * 16 + lr;
            #pragma unroll
            for (int r = 0; r < 4; ++r)
                Om[(size_t)(rbase + r) * 768 + cg] = acc[i][j][r];
        }
    }
}

// ---------------------------------------------------------------------------
// dual-hypothesis validation: bit0 = as-is wrong, bit1 = fragment-transposed wrong
// ---------------------------------------------------------------------------
__global__ __launch_bounds__(64)
void valid_k(const float* __restrict__ T, const float* __restrict__ W1,
             const float* __restrict__ A, const float* __restrict__ Bm,
             int* __restrict__ flag) {
    const int blk = blockIdx.x, lane = threadIdx.x;
    #pragma unroll 1
    for (int j = 0; j < 8; ++j) {
        const int id = blk * 8 + j;
        const int m = (id * 509) & 8191;
        const int n = (id * 251) % 1536;
        const float* w = (n < 768) ? (W1 + n) : (W1 + 768 * 768 + (n - 768));
        float p = 0.f;
        for (int k = lane; k < 768; k += 64)
            p = fmaf(T[(size_t)m * 768 + k], w[(size_t)k * 768], p);
        #pragma unroll
        for (int off = 32; off; off >>= 1) p += __shfl_xor(p, off);
        if (lane == 0) {
            const int nl = (n < 768) ? n : n - 768;
            const float* M = (n < 768) ? A : Bm;
            const float v0 = M[(size_t)m * 768 + nl];
            const int mt = (m & ~15) | (nl & 15);
            const int nt = (nl & ~15) | (m & 15);
            const float v1 = M[(size_t)mt * 768 + nt];
            if (fabsf(p - v0) > 0.02f) atomicOr(flag, 1);
            if (fabsf(p - v1) > 0.02f) atomicOr(flag, 2);
        }
    }
}

// ---------------------------------------------------------------------------
// in-place within-16x16-fragment transpose of A and Bm; runs iff flag == 1
// ---------------------------------------------------------------------------
__global__ __launch_bounds__(256)
void fixtr_k(float* __restrict__ A, float* __restrict__ Bm, const int* __restrict__ flag) {
    if (*flag != 1) return;
    __shared__ float t[64][65];
    float* M = blockIdx.z ? Bm : A;
    const int m0 = blockIdx.x * 64, n0 = blockIdx.y * 64;
    const int tx = threadIdx.x & 63, ty = threadIdx.x >> 6;
    for (int r = ty; r < 64; r += 4)
        t[r][tx] = M[(size_t)(m0 + r) * 768 + n0 + tx];
    __syncthreads();
    for (int r = ty; r < 64; r += 4) {
        const float v = t[(r & ~15) | (tx & 15)][(tx & ~15) | (r & 15)];
        M[(size_t)(m0 + r) * 768 + n0 + tx] = v;
    }
}

// ---------------------------------------------------------------------------
// full fp32 GEMM repair: runs iff flag == 3 (both hypotheses failed)
// ---------------------------------------------------------------------------
__global__ __launch_bounds__(256, 3)
void repair_k(const float* __restrict__ Tm, const float* __restrict__ W1,
              float* __restrict__ Aout, float* __restrict__ Bout,
              const int* __restrict__ flag) {
    if (*flag != 3) return;
    constexpr int K = D_, N = D_;
    __shared__ float As[16][128];
    __shared__ float Bs[16][128];
    const int bm  = blockIdx.x;
    const int bn2 = blockIdx.y;
    const float* W = W1 + (bn2 >= 6 ? (size_t)D_ * D_ : 0);
    float* Om      = (bn2 >= 6) ? Bout : Aout;
    const int bn   = (bn2 >= 6) ? bn2 - 6 : bn2;
    const int tid = threadIdx.x;
    const int row0 = bm * 128, col0 = bn * 128;
    const int tx = tid & 15, ty = tid >> 4;
    float acc[8][8];
    #pragma unroll
    for (int i = 0; i < 8; ++i)
        #pragma unroll
        for (int j = 0; j < 8; ++j) acc[i][j] = 0.f;
    const int arow = tid >> 1;
    const int acol = (tid & 1) * 4;
    const int brow = tid >> 5;
    const int bcol = (tid & 31) * 4;
    const float* Aptr = Tm + (size_t)(row0 + arow) * K + acol;
    const float* Bptr = W  + (size_t)brow * N + col0 + bcol;
    for (int k0 = 0; k0 < K; k0 += 16) {
        #pragma unroll
        for (int r = 0; r < 2; ++r) {
            float4 av = *reinterpret_cast<const float4*>(Aptr + k0 + r * 8);
            As[acol + r*8 + 0][arow] = av.x;
            As[acol + r*8 + 1][arow] = av.y;
            As[acol + r*8 + 2][arow] = av.z;
            As[acol + r*8 + 3][arow] = av.w;
        }
        #pragma unroll
        for (int r = 0; r < 2; ++r) {
            float4 bv = *reinterpret_cast<const float4*>(Bptr + (size_t)(k0 + r*8) * N);
            *reinterpret_cast<float4*>(&Bs[brow + r*8][bcol]) = bv;
        }
        __syncthreads();
        #pragma unroll
        for (int k = 0; k < 16; ++k) {
            float a[8], b[8];
            *reinterpret_cast<float4*>(&a[0]) = *reinterpret_cast<const float4*>(&As[k][ty*8]);
            *reinterpret_cast<float4*>(&a[4]) = *reinterpret_cast<const float4*>(&As[k][ty*8+4]);
            *reinterpret_cast<float4*>(&b[0]) = *reinterpret_cast<const float4*>(&Bs[k][tx*4]);
            *reinterpret_cast<float4*>(&b[4]) = *reinterpret_cast<const float4*>(&Bs[k][tx*4+64]);
            #pragma unroll
            for (int i = 0; i < 8; ++i)
                #pragma unroll
                for (int j = 0; j < 8; ++j)
                    acc[i][j] = fmaf(a[i], b[j], acc[i][j]);
        }
        __syncthreads();
    }
    #pragma unroll
    for (int i = 0; i < 8; ++i) {
        size_t ro = (size_t)(row0 + ty*8 + i) * N + col0;
        float4 v0 = make_float4(acc[i][0], acc[i][1], acc[i][2], acc[i][3]);
        float4 v1 = make_float4(acc[i][4], acc[i][5], acc[i][6], acc[i][7]);
        *reinterpret_cast<float4*>(&Om[ro + tx*4])      = v0;
        *reinterpret_cast<float4*>(&Om[ro + tx*4 + 64]) = v1;
    }
}

// ---------------------------------------------------------------------------
__global__ void w2ws_k(const float* __restrict__ W2, const float* __restrict__ Ws,
                       const float* __restrict__ b2, const float* __restrict__ bs,
                       float* __restrict__ w2ws, float* __restrict__ cc) {
    const int d = blockIdx.x;
    const int lane = threadIdx.x;
    float p = 0.f;
    if (d < D_) {
        const float* row = W2 + (size_t)d * D_;
        for (int i = lane; i < D_; i += 64) p += row[i] * Ws[i];
    } else {
        for (int i = lane; i < D_; i += 64) p += b2[i] * Ws[i];
    }
    #pragma unroll
    for (int off = 32; off; off >>= 1) p += __shfl_xor(p, off);
    if (lane == 0) {
        if (d < D_) w2ws[d] = p;
        else        *cc = p + *bs;
    }
}

__global__ void seqlen_k(const int* __restrict__ mask, int* __restrict__ seqlen) {
    const int b = blockIdx.x;
    const int lane = threadIdx.x;
    int p = 0;
    for (int i = lane; i < S_; i += 64) p += mask[b * S_ + i];
    #pragma unroll
    for (int off = 32; off; off >>= 1) p += __shfl_xor(p, off);
    if (lane == 0) seqlen[b] = p;
}

// ---------------------------------------------------------------------------
__global__ __launch_bounds__(64)
void score_k(const float* __restrict__ A, const float* __restrict__ Bm,
             const float* __restrict__ b1, const float* __restrict__ w2ws,
             const float* __restrict__ cc, const int* __restrict__ seqlen,
             float* __restrict__ scores) {
    const int bsid = blockIdx.x;
    const int b = bsid >> 9, s = bsid & 511;
    const int lane = threadIdx.x;
    float a[12], w[12], bb[12];
    const float* Arow = A + (size_t)bsid * D_;
    #pragma unroll
    for (int i = 0; i < 12; ++i) {
        int d = lane + i * 64;
        a[i]  = Arow[d];
        w[i]  = w2ws[d];
        bb[i] = b1[d];
    }
    const int sl = seqlen[b];
    const float c = *cc;
    #pragma unroll
    for (int w_ = 0; w_ < MAXW; ++w_) {
        const int e = min(s + w_, S_ - 1);
        const float* Brow = Bm + ((size_t)(b << 9) + e) * D_;
        float p = 0.f;
        #pragma unroll
        for (int i = 0; i < 12; ++i) {
            float h = a[i] + Brow[lane + i * 64] + bb[i];
            p = fmaf(fmaxf(h, 0.f), w[i], p);
        }
        #pragma unroll
        for (int off = 32; off; off >>= 1) p += __shfl_xor(p, off);
        if (lane == 0)
            scores[b * NSPAN + s * MAXW + w_] = (s + w_ < sl) ? (p + c) : -1e30f;
    }
}

// ---------------------------------------------------------------------------
__global__ __launch_bounds__(256)
void topk_k(const float* __restrict__ scores, int* __restrict__ cand_idx) {
    __shared__ float sv[NSPAN];
    __shared__ float rv[4];
    __shared__ int   ri[4];
    const int b = blockIdx.x, tid = threadIdx.x;
    for (int i = tid; i < NSPAN; i += 256) sv[i] = scores[b * NSPAN + i];
    __syncthreads();
    for (int k = 0; k < CAND; ++k) {
        float best = -INFINITY; int bi = 1 << 30;
        for (int i = tid; i < NSPAN; i += 256) {
            float v = sv[i];
            if (v > best || (v == best && i < bi)) { best = v; bi = i; }
        }
        #pragma unroll
        for (int off = 32; off; off >>= 1) {
            float ov = __shfl_xor(best, off);
            int   oi = __shfl_xor(bi, off);
            if (ov > best || (ov == best && oi < bi)) { best = ov; bi = oi; }
        }
        if ((tid & 63) == 0) { rv[tid >> 6] = best; ri[tid >> 6] = bi; }
        __syncthreads();
        if (tid == 0) {
            #pragma unroll
            for (int wv = 1; wv < 4; ++wv)
                if (rv[wv] > best || (rv[wv] == best && ri[wv] < bi)) { best = rv[wv]; bi = ri[wv]; }
            cand_idx[b * CAND + k] = bi;
            sv[bi] = -INFINITY;
        }
        __syncthreads();
    }
}

// ---------------------------------------------------------------------------
// exact rerank, split-k partials: grid (64, 4) = (b*4+g, kq); 4 cands/block
// part[kq][cand][d] += T-half-slice · W1-slice   (exact fp32, no A/Bm dep)
// ---------------------------------------------------------------------------
__global__ __launch_bounds__(256)
void rerank_part(const float* __restrict__ T, const float* __restrict__ W1,
                 const int* __restrict__ cand_idx, float* __restrict__ part) {
    __shared__ float tj[4][384];
    const int bx = blockIdx.x, kq = blockIdx.y;
    const int b = bx >> 2, g = bx & 3;
    const int tid = threadIdx.x;
    const int c0 = b * CAND + g * 4;
    const int seg = (kq & 1) * 384;

    #pragma unroll
    for (int j = 0; j < 4; ++j) {
        const int n = cand_idx[c0 + j];
        const int s = n / MAXW, w = n % MAXW;
        const int row = (kq < 2) ? s : min(s + w, S_ - 1);
        const float* src = T + ((size_t)(b * S_ + row)) * D_ + seg;
        for (int idx = tid; idx < 384; idx += 256) tj[j][idx] = src[idx];
    }
    __syncthreads();

    float acc[4][3];
    #pragma unroll
    for (int j = 0; j < 4; ++j)
        #pragma unroll
        for (int q = 0; q < 3; ++q) acc[j][q] = 0.f;

    const int f0 = kq * 384;
    #pragma unroll 2
    for (int ff = 0; ff < 384; ++ff) {
        const float* wr = W1 + (size_t)(f0 + ff) * D_ + tid;
        const float w0 = wr[0];
        const float w1 = wr[256];
        const float w2 = wr[512];
        #pragma unroll
        for (int j = 0; j < 4; ++j) {
            const float tv = tj[j][ff];
            acc[j][0] = fmaf(tv, w0, acc[j][0]);
            acc[j][1] = fmaf(tv, w1, acc[j][1]);
            acc[j][2] = fmaf(tv, w2, acc[j][2]);
        }
    }
    #pragma unroll
    for (int j = 0; j < 4; ++j)
        #pragma unroll
        for (int q = 0; q < 3; ++q)
            part[((size_t)(kq * 256 + c0 + j)) * D_ + tid + q * 256] = acc[j][q];
}

// ---------------------------------------------------------------------------
// reduce partials -> exact h (relu) + exact span score. one block per candidate
// ---------------------------------------------------------------------------
__global__ __launch_bounds__(256)
void rerank_red(const float* __restrict__ part, const float* __restrict__ b1,
                const float* __restrict__ w2ws, const float* __restrict__ cc,
                float* __restrict__ cand_h, float* __restrict__ cand_score) {
    __shared__ float red[4];
    const int c = blockIdx.x, tid = threadIdx.x;
    float p = 0.f;
    #pragma unroll
    for (int q = 0; q < 3; ++q) {
        const int d = tid + q * 256;
        float h = part[((size_t)(0 * 256 + c)) * D_ + d]
                + part[((size_t)(1 * 256 + c)) * D_ + d]
                + part[((size_t)(2 * 256 + c)) * D_ + d]
                + part[((size_t)(3 * 256 + c)) * D_ + d] + b1[d];
        h = fmaxf(h, 0.f);
        cand_h[(size_t)c * D_ + d] = h;
        p = fmaf(h, w2ws[d], p);
    }
    #pragma unroll
    for (int off = 32; off; off >>= 1) p += __shfl_xor(p, off);
    if ((tid & 63) == 0) red[tid >> 6] = p;
    __syncthreads();
    if (tid == 0) cand_score[c] = red[0] + red[1] + red[2] + red[3] + *cc;
}

// ---------------------------------------------------------------------------
__global__ void sel_k(const float* __restrict__ cand_score, const int* __restrict__ cand_idx,
                      float* __restrict__ top_rel, int* __restrict__ sel_slot) {
    const int b = blockIdx.x;
    if (threadIdx.x != 0) return;
    float sc[CAND]; int nn[CAND]; bool used[CAND];
    #pragma unroll
    for (int c = 0; c < CAND; ++c) {
        sc[c] = cand_score[b * CAND + c];
        nn[c] = cand_idx[b * CAND + c];
        used[c] = false;
    }
    for (int k = 0; k < TOPK; ++k) {
        float best = -INFINITY; int bi = -1, bn = 1 << 30;
        #pragma unroll
        for (int c = 0; c < CAND; ++c) {
            if (!used[c] && (sc[c] > best || (sc[c] == best && nn[c] < bn))) {
                best = sc[c]; bi = c; bn = nn[c];
            }
        }
        used[bi] = true;
        top_rel[b * TOPK + k] = best;
        sel_slot[b * TOPK + k] = bi;
    }
}

// ---------------------------------------------------------------------------
__global__ __launch_bounds__(256)
void repr2_k(const float* __restrict__ cand_h, const int* __restrict__ sel_slot,
             const float* __restrict__ W2, const float* __restrict__ b2,
             const float* __restrict__ labels, float* __restrict__ sim) {
    const int blk = blockIdx.x;
    const int b = blk >> 3, kk = blk & 7;
    const int tid = threadIdx.x;
    __shared__ float h[D_];
    __shared__ float sr[D_];
    __shared__ float red[4];

    const int c = sel_slot[b * TOPK + kk];
    const float* hp = cand_h + ((size_t)(b * CAND + c)) * D_;
    for (int d = tid; d < D_; d += 256) h[d] = hp[d];
    __syncthreads();

    float r0 = b2[tid], r1 = b2[tid + 256], r2 = b2[tid + 512];
    for (int d = 0; d < D_; ++d) {
        const float hv = h[d];
        const float* Wrow = W2 + (size_t)d * D_;
        r0 = fmaf(hv, Wrow[tid],       r0);
        r1 = fmaf(hv, Wrow[tid + 256], r1);
        r2 = fmaf(hv, Wrow[tid + 512], r2);
    }
    sr[tid] = r0; sr[tid + 256] = r1; sr[tid + 512] = r2;
    __syncthreads();

    const float* lab = labels + (size_t)b * L_ * D_;
    for (int l = 0; l < L_; ++l) {
        float p = 0.f;
        for (int d = tid; d < D_; d += 256) p = fmaf(lab[l * D_ + d], sr[d], p);
        #pragma unroll
        for (int off = 32; off; off >>= 1) p += __shfl_xor(p, off);
        if ((tid & 63) == 0) red[tid >> 6] = p;
        __syncthreads();
        if (tid == 0) sim[(b * L_ + l) * TOPK + kk] = red[0] + red[1] + red[2] + red[3];
        __syncthreads();
    }
}

// ---------------------------------------------------------------------------
__global__ void final_k(const float* __restrict__ top_rel, const float* __restrict__ sim,
                        float* __restrict__ out) {
    const int b = blockIdx.x, tid = threadIdx.x;
    float m = -INFINITY;
    #pragma unroll
    for (int k = 0; k < TOPK; ++k) m = fmaxf(m, top_rel[b * TOPK + k]);
    float wgt[TOPK]; float Z = 0.f;
    #pragma unroll
    for (int k = 0; k < TOPK; ++k) { wgt[k] = expf(top_rel[b * TOPK + k] - m); Z += wgt[k]; }
    if (tid < L_) {
        float acc = 0.f;
        #pragma unroll
        for (int k = 0; k < TOPK; ++k) acc += sim[(b * L_ + tid) * TOPK + k] * wgt[k];
        const float sc = acc / Z;
        out[b * L_ + tid]            = 1.f / (1.f + expf(-sc));
        out[B_ * L_ + b * L_ + tid]  = 1.0f;
    }
}

// ---------------------------------------------------------------------------
extern "C" void kernel_launch(void* const* d_in, const int* in_sizes, int n_in,
                              void* d_out, int out_size, void* d_ws, size_t ws_size,
                              hipStream_t stream) {
    (void)in_sizes; (void)n_in; (void)out_size;
    const float* token_embs = (const float*)d_in[0];
    const int*   token_mask = (const int*)  d_in[1];
    const float* label_embs = (const float*)d_in[2];
    const float* W1 = (const float*)d_in[3];
    const float* b1 = (const float*)d_in[4];
    const float* W2 = (const float*)d_in[5];
    const float* b2 = (const float*)d_in[6];
    const float* Ws = (const float*)d_in[7];
    const float* bs = (const float*)d_in[8];
    float* out = (float*)d_out;

    float* A          = (float*)d_ws;                   // 6291456 f32
    float* Bm         = A + (size_t)M_ * D_;            // 6291456 f32
    float* scores     = Bm + (size_t)M_ * D_;           // 40960
    float* w2ws       = scores + B_ * NSPAN;            // 768
    float* cc         = w2ws + D_;                      // 1
    int*   seqlen     = (int*)(cc + 1);                 // 16
    int*   flag       = seqlen + B_;                    // 1
    float* top_rel    = (float*)(flag + 1);             // 128
    int*   sel_slot   = (int*)(top_rel + B_ * TOPK);    // 128
    int*   cand_idx   = sel_slot + B_ * TOPK;           // 256
    float* cand_score = (float*)(cand_idx + B_ * CAND); // 256
    float* sim        = cand_score + B_ * CAND;         // 640
    // A region is dead after topk_k -> reuse for rerank partials + exact h
    float* part       = A;                              // 4*256*768 = 786432 f32
    float* cand_h     = A + 786432;                     // 256*768   = 196608 f32

    ushort* Thi  = (ushort*)(A + 12648448);
    ushort* Tlo  = Thi + (size_t)M_ * D_;
    ushort* WhiT = Tlo + (size_t)M_ * D_;
    ushort* WloT = WhiT + (size_t)2 * D_ * D_;
    const size_t need = 12648448ULL * 4 + (2ULL * M_ * D_ + 4ULL * D_ * D_) * 2;
    const bool use_mfma = (ws_size >= need);

    init_k<<<1, 64, 0, stream>>>(flag, use_mfma ? 0 : 3);
    if (use_mfma) {
        cvt_T<<<(M_ * D_) / (256 * 4), 256, 0, stream>>>(token_embs, Thi, Tlo);
        cvt_W<<<dim3(24, 48), 256, 0, stream>>>(W1, WhiT, WloT);
        mm_k <<<dim3(64, 12), 256, 0, stream>>>(Thi, Tlo, WhiT, WloT, A, Bm);
        valid_k<<<256, 64, 0, stream>>>(token_embs, W1, A, Bm, flag);
    }
    fixtr_k <<<dim3(128, 12, 2), 256, 0, stream>>>(A, Bm, flag);
    repair_k<<<dim3(64, 12), 256, 0, stream>>>(token_embs, W1, A, Bm, flag);
    w2ws_k  <<<D_ + 1, 64, 0, stream>>>(W2, Ws, b2, bs, w2ws, cc);
    seqlen_k<<<B_, 64, 0, stream>>>(token_mask, seqlen);
    score_k <<<M_, 64, 0, stream>>>(A, Bm, b1, w2ws, cc, seqlen, scores);
    topk_k  <<<B_, 256, 0, stream>>>(scores, cand_idx);
    rerank_part<<<dim3(64, 4), 256, 0, stream>>>(token_embs, W1, cand_idx, part);
    rerank_red <<<256, 256, 0, stream>>>(part, b1, w2ws, cc, cand_h, cand_score);
    sel_k   <<<B_, 64, 0, stream>>>(cand_score, cand_idx, top_rel, sel_slot);
    repr2_k <<<B_ * TOPK, 256, 0, stream>>>(cand_h, sel_slot, W2, b2, label_embs, sim);
    final_k <<<B_, 64, 0, stream>>>(top_rel, sim, out);
}

// Round 6
// 542.268 us; speedup vs baseline: 1.3632x; 1.0174x over previous
//
#include <hip/hip_runtime.h>
#include <math.h>

#define B_    16
#define S_    512
#define D_    768
#define L_    5
#define MAXW  5
#define TOPK  8
#define CAND  16
#define NSPAN (S_*MAXW)    // 2560
#define M_    (B_*S_)      // 8192

typedef __attribute__((ext_vector_type(8))) short s16x8;
typedef __attribute__((ext_vector_type(4))) float f32x4;

__device__ __forceinline__ ushort f2bf(float x) {
    union { float f; unsigned u; } c; c.f = x;
    unsigned r = c.u + 0x7fffu + ((c.u >> 16) & 1u);
    return (ushort)(r >> 16);
}
__device__ __forceinline__ float bf2f(ushort h) {
    union { unsigned u; float f; } c; c.u = ((unsigned)h) << 16;
    return c.f;
}

// ---------------------------------------------------------------------------
__global__ void init_k(int* __restrict__ flag, int v) {
    if (threadIdx.x == 0) *flag = v;
}

// ---------------------------------------------------------------------------
// On-device MFMA layout probe. One wave, registers only (no LDS staging, no
// global fragment loads) -> isolates the intrinsic's true lane->(row,col)
// output mapping given our assumed A/B fragment packing.
//   A[m][k] = (k==0)?(m+1):((k==1)?1:0)
//   B[k][n] = (k==0)?1:((k==1)?32*(n+1):0)
//   => D[m][n] = (m+1) + 32*(n+1), all exact in bf16/fp32, 256 distinct codes.
// Fragments packed per assumption: lane l supplies A[l&15][8*(l>>4)+r] and
// B[8*(l>>4)+r][l&15]. Decoded (m,n) per (lane,reg) -> rowMap/colMap.
// Any decode failure or non-bijective result -> flag |= 4 (repair path).
// ---------------------------------------------------------------------------
__global__ __launch_bounds__(64)
void probe_k(int* __restrict__ rowMap, int* __restrict__ colMap, int* __restrict__ flag) {
    __shared__ int seen[256];
    const int l = threadIdx.x;
    const int lr = l & 15, lg = l >> 4;
    #pragma unroll
    for (int r = 0; r < 4; ++r) seen[l * 4 + r] = 0;
    __syncthreads();

    s16x8 af, bf;
    #pragma unroll
    for (int r = 0; r < 8; ++r) {
        const int k = lg * 8 + r;
        const float av = (k == 0) ? (float)(lr + 1) : ((k == 1) ? 1.f : 0.f);
        const float bv = (k == 0) ? 1.f : ((k == 1) ? 32.f * (float)(lr + 1) : 0.f);
        af[r] = (short)f2bf(av);
        bf[r] = (short)f2bf(bv);
    }
    f32x4 z = {0.f, 0.f, 0.f, 0.f};
    f32x4 d = __builtin_amdgcn_mfma_f32_16x16x32_bf16(af, bf, z, 0, 0, 0);

    int mloc[4], nloc[4];
    bool ok = true;
    #pragma unroll
    for (int r = 0; r < 4; ++r) {
        const float dv = d[r];
        int m, n;
        if (dv >= 32.5f && dv <= 528.5f) {
            const int v = (int)(dv + 0.5f);
            m = (v & 31) - 1;
            n = (v >> 5) - 1;
            if (dv != (float)v || m < 0 || m > 15 || n < 0 || n > 15) {
                ok = false; m = lg * 4 + r; n = lr;
            }
        } else {
            ok = false; m = lg * 4 + r; n = lr;
        }
        mloc[r] = m; nloc[r] = n;
        rowMap[l * 4 + r] = m;
        colMap[l * 4 + r] = n;
    }
    if (!ok) atomicOr(flag, 4);
    #pragma unroll
    for (int r = 0; r < 4; ++r) atomicAdd(&seen[mloc[r] * 16 + nloc[r]], 1);
    __syncthreads();
    #pragma unroll
    for (int r = 0; r < 4; ++r)
        if (seen[l * 4 + r] != 1) atomicOr(flag, 4);
}

// ---------------------------------------------------------------------------
__global__ __launch_bounds__(256)
void cvt_T(const float* __restrict__ X, ushort* __restrict__ hi, ushort* __restrict__ lo) {
    const int i = (blockIdx.x * 256 + threadIdx.x) * 4;
    float4 v = *reinterpret_cast<const float4*>(X + i);
    ushort4 h, l;
    h.x = f2bf(v.x); l.x = f2bf(v.x - bf2f(h.x));
    h.y = f2bf(v.y); l.y = f2bf(v.y - bf2f(h.y));
    h.z = f2bf(v.z); l.z = f2bf(v.z - bf2f(h.z));
    h.w = f2bf(v.w); l.w = f2bf(v.w - bf2f(h.w));
    *reinterpret_cast<ushort4*>(hi + i) = h;
    *reinterpret_cast<ushort4*>(lo + i) = l;
}

// ---------------------------------------------------------------------------
__global__ __launch_bounds__(256)
void cvt_W(const float* __restrict__ W1, ushort* __restrict__ Whi, ushort* __restrict__ Wlo) {
    __shared__ float tl[32][33];
    const int k0 = blockIdx.x * 32, n0 = blockIdx.y * 32;
    const int tx = threadIdx.x & 31, ty = threadIdx.x >> 5;
    const int base = (n0 >= 768) ? 768 : 0;
    const int d0 = n0 & 767;
    #pragma unroll
    for (int it = 0; it < 4; ++it) {
        int rr = ty + it * 8;
        tl[rr][tx] = W1[(size_t)(base + k0 + rr) * 768 + d0 + tx];
    }
    __syncthreads();
    #pragma unroll
    for (int it = 0; it < 4; ++it) {
        int rr = ty + it * 8;
        float v = tl[tx][rr];
        ushort h = f2bf(v);
        size_t o = (size_t)(n0 + rr) * 768 + k0 + tx;
        Whi[o] = h;
        Wlo[o] = f2bf(v - bf2f(h));
    }
}

// ---------------------------------------------------------------------------
// MFMA GEMM — same math as R3/R5, but the C-write goes through the
// probe-discovered (rowMap,colMap) so any composite fragment/CD permutation
// is auto-corrected.
// ---------------------------------------------------------------------------
__global__ __launch_bounds__(256)
void mm_k(const ushort* __restrict__ Thi, const ushort* __restrict__ Tlo,
          const ushort* __restrict__ Whi, const ushort* __restrict__ Wlo,
          const int* __restrict__ rowMap, const int* __restrict__ colMap,
          float* __restrict__ Aout, float* __restrict__ Bout) {
    __shared__ __align__(16) ushort As[128 * 32];
    __shared__ __align__(16) ushort Bs[128 * 32];
    const int tid = threadIdx.x;
    const int bm = blockIdx.x, bn = blockIdx.y;
    const int row0 = bm * 128;
    const int n0g = bn * 128;

    const int srow = tid >> 2;
    const int scol = (tid & 3) * 8;
    const size_t a_g0 = (size_t)(row0 + srow) * 768 + scol;
    const size_t b_g0 = (size_t)(n0g + srow) * 768 + scol;
    const int l_off = srow * 32 + scol;

    const int lane = tid & 63, wv = tid >> 6;
    const int wr = wv >> 1, wc = wv & 1;
    const int lr = lane & 15, lg = lane >> 4;
    const int ko = lg * 8;

    int rm[4], cm[4];
    #pragma unroll
    for (int r = 0; r < 4; ++r) {
        rm[r] = rowMap[lane * 4 + r];
        cm[r] = colMap[lane * 4 + r];
    }

    f32x4 acc[4][4];
    #pragma unroll
    for (int i = 0; i < 4; ++i)
        #pragma unroll
        for (int j = 0; j < 4; ++j) acc[i][j] = f32x4{0.f, 0.f, 0.f, 0.f};

    #pragma unroll 1
    for (int ph = 0; ph < 3; ++ph) {
        const ushort* Asrc = (ph == 1) ? Tlo : Thi;
        const ushort* Bsrc = (ph == 2) ? Wlo : Whi;
        #pragma unroll 1
        for (int jj = 0; jj < 24; ++jj) {
            const int col = jj * 32;
            uint4 a0 = *reinterpret_cast<const uint4*>(Asrc + a_g0 + col);
            uint4 a1 = *reinterpret_cast<const uint4*>(Asrc + a_g0 + col + 64 * 768);
            uint4 b0 = *reinterpret_cast<const uint4*>(Bsrc + b_g0 + col);
            uint4 b1 = *reinterpret_cast<const uint4*>(Bsrc + b_g0 + col + 64 * 768);
            __syncthreads();
            *reinterpret_cast<uint4*>(&As[l_off])           = a0;
            *reinterpret_cast<uint4*>(&As[l_off + 64 * 32]) = a1;
            *reinterpret_cast<uint4*>(&Bs[l_off])           = b0;
            *reinterpret_cast<uint4*>(&Bs[l_off + 64 * 32]) = b1;
            __syncthreads();
            s16x8 af[4], bf[4];
            #pragma unroll
            for (int i = 0; i < 4; ++i)
                af[i] = *reinterpret_cast<const s16x8*>(&As[(wr * 64 + i * 16 + lr) * 32 + ko]);
            #pragma unroll
            for (int j = 0; j < 4; ++j)
                bf[j] = *reinterpret_cast<const s16x8*>(&Bs[(wc * 64 + j * 16 + lr) * 32 + ko]);
            #pragma unroll
            for (int i = 0; i < 4; ++i)
                #pragma unroll
                for (int j = 0; j < 4; ++j)
                    acc[i][j] = __builtin_amdgcn_mfma_f32_16x16x32_bf16(af[i], bf[j], acc[i][j], 0, 0, 0);
        }
    }

    float* Om = (bn < 6) ? Aout : Bout;
    const int cbase = ((bn < 6) ? bn : bn - 6) * 128 + wc * 64;
    #pragma unroll
    for (int i = 0; i < 4; ++i)
        #pragma unroll
        for (int j = 0; j < 4; ++j)
            #pragma unroll
            for (int r = 0; r < 4; ++r)
                Om[(size_t)(row0 + wr * 64 + i * 16 + rm[r]) * 768 + cbase + j * 16 + cm[r]]
                    = acc[i][j][r];
}

// ---------------------------------------------------------------------------
// sampled validation of A/Bm vs exact fp32 dots; mismatch -> flag |= 1
// ---------------------------------------------------------------------------
__global__ __launch_bounds__(64)
void valid_k(const float* __restrict__ T, const float* __restrict__ W1,
             const float* __restrict__ A, const float* __restrict__ Bm,
             int* __restrict__ flag) {
    const int blk = blockIdx.x, lane = threadIdx.x;
    #pragma unroll 1
    for (int j = 0; j < 8; ++j) {
        const int id = blk * 8 + j;
        const int m = (id * 509) & 8191;
        const int n = (id * 251) % 1536;
        const float* w = (n < 768) ? (W1 + n) : (W1 + 768 * 768 + (n - 768));
        float p = 0.f;
        for (int k = lane; k < 768; k += 64)
            p = fmaf(T[(size_t)m * 768 + k], w[(size_t)k * 768], p);
        #pragma unroll
        for (int off = 32; off; off >>= 1) p += __shfl_xor(p, off);
        if (lane == 0) {
            const int nl = (n < 768) ? n : n - 768;
            const float* M = (n < 768) ? A : Bm;
            if (fabsf(p - M[(size_t)m * 768 + nl]) > 0.02f) atomicOr(flag, 1);
        }
    }
}

// ---------------------------------------------------------------------------
// full fp32 GEMM repair: runs iff flag != 0
// ---------------------------------------------------------------------------
__global__ __launch_bounds__(256, 3)
void repair_k(const float* __restrict__ Tm, const float* __restrict__ W1,
              float* __restrict__ Aout, float* __restrict__ Bout,
              const int* __restrict__ flag) {
    if (*flag == 0) return;
    constexpr int K = D_, N = D_;
    __shared__ float As[16][128];
    __shared__ float Bs[16][128];
    const int bm  = blockIdx.x;
    const int bn2 = blockIdx.y;
    const float* W = W1 + (bn2 >= 6 ? (size_t)D_ * D_ : 0);
    float* Om      = (bn2 >= 6) ? Bout : Aout;
    const int bn   = (bn2 >= 6) ? bn2 - 6 : bn2;
    const int tid = threadIdx.x;
    const int row0 = bm * 128, col0 = bn * 128;
    const int tx = tid & 15, ty = tid >> 4;
    float acc[8][8];
    #pragma unroll
    for (int i = 0; i < 8; ++i)
        #pragma unroll
        for (int j = 0; j < 8; ++j) acc[i][j] = 0.f;
    const int arow = tid >> 1;
    const int acol = (tid & 1) * 4;
    const int brow = tid >> 5;
    const int bcol = (tid & 31) * 4;
    const float* Aptr = Tm + (size_t)(row0 + arow) * K + acol;
    const float* Bptr = W  + (size_t)brow * N + col0 + bcol;
    for (int k0 = 0; k0 < K; k0 += 16) {
        #pragma unroll
        for (int r = 0; r < 2; ++r) {
            float4 av = *reinterpret_cast<const float4*>(Aptr + k0 + r * 8);
            As[acol + r*8 + 0][arow] = av.x;
            As[acol + r*8 + 1][arow] = av.y;
            As[acol + r*8 + 2][arow] = av.z;
            As[acol + r*8 + 3][arow] = av.w;
        }
        #pragma unroll
        for (int r = 0; r < 2; ++r) {
            float4 bv = *reinterpret_cast<const float4*>(Bptr + (size_t)(k0 + r*8) * N);
            *reinterpret_cast<float4*>(&Bs[brow + r*8][bcol]) = bv;
        }
        __syncthreads();
        #pragma unroll
        for (int k = 0; k < 16; ++k) {
            float a[8], b[8];
            *reinterpret_cast<float4*>(&a[0]) = *reinterpret_cast<const float4*>(&As[k][ty*8]);
            *reinterpret_cast<float4*>(&a[4]) = *reinterpret_cast<const float4*>(&As[k][ty*8+4]);
            *reinterpret_cast<float4*>(&b[0]) = *reinterpret_cast<const float4*>(&Bs[k][tx*4]);
            *reinterpret_cast<float4*>(&b[4]) = *reinterpret_cast<const float4*>(&Bs[k][tx*4+64]);
            #pragma unroll
            for (int i = 0; i < 8; ++i)
                #pragma unroll
                for (int j = 0; j < 8; ++j)
                    acc[i][j] = fmaf(a[i], b[j], acc[i][j]);
        }
        __syncthreads();
    }
    #pragma unroll
    for (int i = 0; i < 8; ++i) {
        size_t ro = (size_t)(row0 + ty*8 + i) * N + col0;
        float4 v0 = make_float4(acc[i][0], acc[i][1], acc[i][2], acc[i][3]);
        float4 v1 = make_float4(acc[i][4], acc[i][5], acc[i][6], acc[i][7]);
        *reinterpret_cast<float4*>(&Om[ro + tx*4])      = v0;
        *reinterpret_cast<float4*>(&Om[ro + tx*4 + 64]) = v1;
    }
}

// ---------------------------------------------------------------------------
__global__ void w2ws_k(const float* __restrict__ W2, const float* __restrict__ Ws,
                       const float* __restrict__ b2, const float* __restrict__ bs,
                       float* __restrict__ w2ws, float* __restrict__ cc) {
    const int d = blockIdx.x;
    const int lane = threadIdx.x;
    float p = 0.f;
    if (d < D_) {
        const float* row = W2 + (size_t)d * D_;
        for (int i = lane; i < D_; i += 64) p += row[i] * Ws[i];
    } else {
        for (int i = lane; i < D_; i += 64) p += b2[i] * Ws[i];
    }
    #pragma unroll
    for (int off = 32; off; off >>= 1) p += __shfl_xor(p, off);
    if (lane == 0) {
        if (d < D_) w2ws[d] = p;
        else        *cc = p + *bs;
    }
}

__global__ void seqlen_k(const int* __restrict__ mask, int* __restrict__ seqlen) {
    const int b = blockIdx.x;
    const int lane = threadIdx.x;
    int p = 0;
    for (int i = lane; i < S_; i += 64) p += mask[b * S_ + i];
    #pragma unroll
    for (int off = 32; off; off >>= 1) p += __shfl_xor(p, off);
    if (lane == 0) seqlen[b] = p;
}

// ---------------------------------------------------------------------------
__global__ __launch_bounds__(64)
void score_k(const float* __restrict__ A, const float* __restrict__ Bm,
             const float* __restrict__ b1, const float* __restrict__ w2ws,
             const float* __restrict__ cc, const int* __restrict__ seqlen,
             float* __restrict__ scores) {
    const int bsid = blockIdx.x;
    const int b = bsid >> 9, s = bsid & 511;
    const int lane = threadIdx.x;
    float a[12], w[12], bb[12];
    const float* Arow = A + (size_t)bsid * D_;
    #pragma unroll
    for (int i = 0; i < 12; ++i) {
        int d = lane + i * 64;
        a[i]  = Arow[d];
        w[i]  = w2ws[d];
        bb[i] = b1[d];
    }
    const int sl = seqlen[b];
    const float c = *cc;
    #pragma unroll
    for (int w_ = 0; w_ < MAXW; ++w_) {
        const int e = min(s + w_, S_ - 1);
        const float* Brow = Bm + ((size_t)(b << 9) + e) * D_;
        float p = 0.f;
        #pragma unroll
        for (int i = 0; i < 12; ++i) {
            float h = a[i] + Brow[lane + i * 64] + bb[i];
            p = fmaf(fmaxf(h, 0.f), w[i], p);
        }
        #pragma unroll
        for (int off = 32; off; off >>= 1) p += __shfl_xor(p, off);
        if (lane == 0)
            scores[b * NSPAN + s * MAXW + w_] = (s + w_ < sl) ? (p + c) : -1e30f;
    }
}

// ---------------------------------------------------------------------------
__global__ __launch_bounds__(256)
void topk_k(const float* __restrict__ scores, int* __restrict__ cand_idx) {
    __shared__ float sv[NSPAN];
    __shared__ float rv[4];
    __shared__ int   ri[4];
    const int b = blockIdx.x, tid = threadIdx.x;
    for (int i = tid; i < NSPAN; i += 256) sv[i] = scores[b * NSPAN + i];
    __syncthreads();
    for (int k = 0; k < CAND; ++k) {
        float best = -INFINITY; int bi = 1 << 30;
        for (int i = tid; i < NSPAN; i += 256) {
            float v = sv[i];
            if (v > best || (v == best && i < bi)) { best = v; bi = i; }
        }
        #pragma unroll
        for (int off = 32; off; off >>= 1) {
            float ov = __shfl_xor(best, off);
            int   oi = __shfl_xor(bi, off);
            if (ov > best || (ov == best && oi < bi)) { best = ov; bi = oi; }
        }
        if ((tid & 63) == 0) { rv[tid >> 6] = best; ri[tid >> 6] = bi; }
        __syncthreads();
        if (tid == 0) {
            #pragma unroll
            for (int wv = 1; wv < 4; ++wv)
                if (rv[wv] > best || (rv[wv] == best && ri[wv] < bi)) { best = rv[wv]; bi = ri[wv]; }
            cand_idx[b * CAND + k] = bi;
            sv[bi] = -INFINITY;
        }
        __syncthreads();
    }
}

// ---------------------------------------------------------------------------
__global__ __launch_bounds__(256)
void rerank_part(const float* __restrict__ T, const float* __restrict__ W1,
                 const int* __restrict__ cand_idx, float* __restrict__ part) {
    __shared__ float tj[4][384];
    const int bx = blockIdx.x, kq = blockIdx.y;
    const int b = bx >> 2, g = bx & 3;
    const int tid = threadIdx.x;
    const int c0 = b * CAND + g * 4;
    const int seg = (kq & 1) * 384;

    #pragma unroll
    for (int j = 0; j < 4; ++j) {
        const int n = cand_idx[c0 + j];
        const int s = n / MAXW, w = n % MAXW;
        const int row = (kq < 2) ? s : min(s + w, S_ - 1);
        const float* src = T + ((size_t)(b * S_ + row)) * D_ + seg;
        for (int idx = tid; idx < 384; idx += 256) tj[j][idx] = src[idx];
    }
    __syncthreads();

    float acc[4][3];
    #pragma unroll
    for (int j = 0; j < 4; ++j)
        #pragma unroll
        for (int q = 0; q < 3; ++q) acc[j][q] = 0.f;

    const int f0 = kq * 384;
    #pragma unroll 2
    for (int ff = 0; ff < 384; ++ff) {
        const float* wr = W1 + (size_t)(f0 + ff) * D_ + tid;
        const float w0 = wr[0];
        const float w1 = wr[256];
        const float w2 = wr[512];
        #pragma unroll
        for (int j = 0; j < 4; ++j) {
            const float tv = tj[j][ff];
            acc[j][0] = fmaf(tv, w0, acc[j][0]);
            acc[j][1] = fmaf(tv, w1, acc[j][1]);
            acc[j][2] = fmaf(tv, w2, acc[j][2]);
        }
    }
    #pragma unroll
    for (int j = 0; j < 4; ++j)
        #pragma unroll
        for (int q = 0; q < 3; ++q)
            part[((size_t)(kq * 256 + c0 + j)) * D_ + tid + q * 256] = acc[j][q];
}

// ---------------------------------------------------------------------------
__global__ __launch_bounds__(256)
void rerank_red(const float* __restrict__ part, const float* __restrict__ b1,
                const float* __restrict__ w2ws, const float* __restrict__ cc,
                float* __restrict__ cand_h, float* __restrict__ cand_score) {
    __shared__ float red[4];
    const int c = blockIdx.x, tid = threadIdx.x;
    float p = 0.f;
    #pragma unroll
    for (int q = 0; q < 3; ++q) {
        const int d = tid + q * 256;
        float h = part[((size_t)(0 * 256 + c)) * D_ + d]
                + part[((size_t)(1 * 256 + c)) * D_ + d]
                + part[((size_t)(2 * 256 + c)) * D_ + d]
                + part[((size_t)(3 * 256 + c)) * D_ + d] + b1[d];
        h = fmaxf(h, 0.f);
        cand_h[(size_t)c * D_ + d] = h;
        p = fmaf(h, w2ws[d], p);
    }
    #pragma unroll
    for (int off = 32; off; off >>= 1) p += __shfl_xor(p, off);
    if ((tid & 63) == 0) red[tid >> 6] = p;
    __syncthreads();
    if (tid == 0) cand_score[c] = red[0] + red[1] + red[2] + red[3] + *cc;
}

// ---------------------------------------------------------------------------
__global__ void sel_k(const float* __restrict__ cand_score, const int* __restrict__ cand_idx,
                      float* __restrict__ top_rel, int* __restrict__ sel_slot) {
    const int b = blockIdx.x;
    if (threadIdx.x != 0) return;
    float sc[CAND]; int nn[CAND]; bool used[CAND];
    #pragma unroll
    for (int c = 0; c < CAND; ++c) {
        sc[c] = cand_score[b * CAND + c];
        nn[c] = cand_idx[b * CAND + c];
        used[c] = false;
    }
    for (int k = 0; k < TOPK; ++k) {
        float best = -INFINITY; int bi = -1, bn = 1 << 30;
        #pragma unroll
        for (int c = 0; c < CAND; ++c) {
            if (!used[c] && (sc[c] > best || (sc[c] == best && nn[c] < bn))) {
                best = sc[c]; bi = c; bn = nn[c];
            }
        }
        used[bi] = true;
        top_rel[b * TOPK + k] = best;
        sel_slot[b * TOPK + k] = bi;
    }
}

// ---------------------------------------------------------------------------
__global__ __launch_bounds__(256)
void repr2_k(const float* __restrict__ cand_h, const int* __restrict__ sel_slot,
             const float* __restrict__ W2, const float* __restrict__ b2,
             const float* __restrict__ labels, float* __restrict__ sim) {
    const int blk = blockIdx.x;
    const int b = blk >> 3, kk = blk & 7;
    const int tid = threadIdx.x;
    __shared__ float h[D_];
    __shared__ float sr[D_];
    __shared__ float red[4];

    const int c = sel_slot[b * TOPK + kk];
    const float* hp = cand_h + ((size_t)(b * CAND + c)) * D_;
    for (int d = tid; d < D_; d += 256) h[d] = hp[d];
    __syncthreads();

    float r0 = b2[tid], r1 = b2[tid + 256], r2 = b2[tid + 512];
    for (int d = 0; d < D_; ++d) {
        const float hv = h[d];
        const float* Wrow = W2 + (size_t)d * D_;
        r0 = fmaf(hv, Wrow[tid],       r0);
        r1 = fmaf(hv, Wrow[tid + 256], r1);
        r2 = fmaf(hv, Wrow[tid + 512], r2);
    }
    sr[tid] = r0; sr[tid + 256] = r1; sr[tid + 512] = r2;
    __syncthreads();

    const float* lab = labels + (size_t)b * L_ * D_;
    for (int l = 0; l < L_; ++l) {
        float p = 0.f;
        for (int d = tid; d < D_; d += 256) p = fmaf(lab[l * D_ + d], sr[d], p);
        #pragma unroll
        for (int off = 32; off; off >>= 1) p += __shfl_xor(p, off);
        if ((tid & 63) == 0) red[tid >> 6] = p;
        __syncthreads();
        if (tid == 0) sim[(b * L_ + l) * TOPK + kk] = red[0] + red[1] + red[2] + red[3];
        __syncthreads();
    }
}

// ---------------------------------------------------------------------------
__global__ void final_k(const float* __restrict__ top_rel, const float* __restrict__ sim,
                        float* __restrict__ out) {
    const int b = blockIdx.x, tid = threadIdx.x;
    float m = -INFINITY;
    #pragma unroll
    for (int k = 0; k < TOPK; ++k) m = fmaxf(m, top_rel[b * TOPK + k]);
    float wgt[TOPK]; float Z = 0.f;
    #pragma unroll
    for (int k = 0; k < TOPK; ++k) { wgt[k] = expf(top_rel[b * TOPK + k] - m); Z += wgt[k]; }
    if (tid < L_) {
        float acc = 0.f;
        #pragma unroll
        for (int k = 0; k < TOPK; ++k) acc += sim[(b * L_ + tid) * TOPK + k] * wgt[k];
        const float sc = acc / Z;
        out[b * L_ + tid]            = 1.f / (1.f + expf(-sc));
        out[B_ * L_ + b * L_ + tid]  = 1.0f;
    }
}

// ---------------------------------------------------------------------------
extern "C" void kernel_launch(void* const* d_in, const int* in_sizes, int n_in,
                              void* d_out, int out_size, void* d_ws, size_t ws_size,
                              hipStream_t stream) {
    (void)in_sizes; (void)n_in; (void)out_size;
    const float* token_embs = (const float*)d_in[0];
    const int*   token_mask = (const int*)  d_in[1];
    const float* label_embs = (const float*)d_in[2];
    const float* W1 = (const float*)d_in[3];
    const float* b1 = (const float*)d_in[4];
    const float* W2 = (const float*)d_in[5];
    const float* b2 = (const float*)d_in[6];
    const float* Ws = (const float*)d_in[7];
    const float* bs = (const float*)d_in[8];
    float* out = (float*)d_out;

    float* A          = (float*)d_ws;                   // 6291456 f32
    float* Bm         = A + (size_t)M_ * D_;            // 6291456 f32
    float* scores     = Bm + (size_t)M_ * D_;           // 40960
    float* w2ws       = scores + B_ * NSPAN;            // 768
    float* cc         = w2ws + D_;                      // 1
    int*   seqlen     = (int*)(cc + 1);                 // 16
    int*   flag       = seqlen + B_;                    // 1
    float* top_rel    = (float*)(flag + 1);             // 128
    int*   sel_slot   = (int*)(top_rel + B_ * TOPK);    // 128
    int*   cand_idx   = sel_slot + B_ * TOPK;           // 256
    float* cand_score = (float*)(cand_idx + B_ * CAND); // 256
    float* sim        = cand_score + B_ * CAND;         // 640
    int*   rowMap     = (int*)(sim + 640);              // 256
    int*   colMap     = rowMap + 256;                   // 256
    float* part       = A;                              // 786432 f32 (A dead after topk)
    float* cand_h     = A + 786432;                     // 196608 f32

    ushort* Thi  = (ushort*)(A + 12648448);
    ushort* Tlo  = Thi + (size_t)M_ * D_;
    ushort* WhiT = Tlo + (size_t)M_ * D_;
    ushort* WloT = WhiT + (size_t)2 * D_ * D_;
    const size_t need = 12648448ULL * 4 + (2ULL * M_ * D_ + 4ULL * D_ * D_) * 2;
    const bool use_mfma = (ws_size >= need);

    init_k<<<1, 64, 0, stream>>>(flag, use_mfma ? 0 : 3);
    if (use_mfma) {
        probe_k<<<1, 64, 0, stream>>>(rowMap, colMap, flag);
        cvt_T<<<(M_ * D_) / (256 * 4), 256, 0, stream>>>(token_embs, Thi, Tlo);
        cvt_W<<<dim3(24, 48), 256, 0, stream>>>(W1, WhiT, WloT);
        mm_k <<<dim3(64, 12), 256, 0, stream>>>(Thi, Tlo, WhiT, WloT, rowMap, colMap, A, Bm);
        valid_k<<<256, 64, 0, stream>>>(token_embs, W1, A, Bm, flag);
    }
    repair_k<<<dim3(64, 12), 256, 0, stream>>>(token_embs, W1, A, Bm, flag);
    w2ws_k  <<<D_ + 1, 64, 0, stream>>>(W2, Ws, b2, bs, w2ws, cc);
    seqlen_k<<<B_, 64, 0, stream>>>(token_mask, seqlen);
    score_k <<<M_, 64, 0, stream>>>(A, Bm, b1, w2ws, cc, seqlen, scores);
    topk_k  <<<B_, 256, 0, stream>>>(scores, cand_idx);
    rerank_part<<<dim3(64, 4), 256, 0, stream>>>(token_embs, W1, cand_idx, part);
    rerank_red <<<256, 256, 0, stream>>>(part, b1, w2ws, cc, cand_h, cand_score);
    sel_k   <<<B_, 64, 0, stream>>>(cand_score, cand_idx, top_rel, sel_slot);
    repr2_k <<<B_ * TOPK, 256, 0, stream>>>(cand_h, sel_slot, W2, b2, label_embs, sim);
    final_k <<<B_, 64, 0, stream>>>(top_rel, sim, out);
}